// Round 5
// baseline (195.529 us; speedup 1.0000x reference)
//
#include <hip/hip_runtime.h>

// CombinedLoss: chamfer(pred,gt) + 0.1*repulsion(pred,k=4) + 0.01*(1 - mean(n_pred . n_gt))
// B=8, N=2048, fp32 in, fp32 scalar out.
// Normals match np.linalg.eigh (LAPACK ssyevd) signs point-by-point via faithful
// fp32 ssytd2+ssteqr+sormtr emulation (R3-R7: absmax 0.0).
// R8: branchless sorted-chain top-10 per wave-slice, exact top-16 via 8x10 pool
// merge + violation-detect + rare rescan fallback.
// R9: eigensolver state in named registers (cndmask dynamic indexing).
// R10: split kernels -> ~10us/launch x5 ate the win; tail ~45us at 1 wave/block.
// R11/R12: cooperative kernel with grid.sync. FAILED DETERMINISTICALLY with
// out[0]=0 (absmax == ref value 1.35e-2): hipLaunchCooperativeKernel is NOT
// executed by the harness's graph-capture path. Lesson: cross-block visibility
// must come from KERNEL BOUNDARIES (stream order), which R10 proved works.
// R13: fused scan + 8-way-parallel tail (R11's good part) as a NORMAL launch;
// normals + per-block cd partials via plain stores; then dot_kernel (16 blocks,
// exact R10 fp32 order, plain-stores dotpart) + fin_kernel (1 block reduces
// 512 cdpart + 16 dotpart, writes out). 3 launches, no memset, no atomics.

#define NB 8
#define NP 2048
#define KW 10     // per-slice kept keys
#define KN 16

// ---------------- LAPACK helpers (fp32, faithful — DO NOT TOUCH) ----------------

__device__ __forceinline__ float f_slapy2(float x, float y) {
    float xa = fabsf(x), ya = fabsf(y);
    float w = fmaxf(xa, ya), zm = fminf(xa, ya);
    if (zm == 0.f) return w;
    float q = zm / w;
    return w * sqrtf(1.f + q * q);
}

// LAPACK >=3.10 slartg convention: c >= 0 always.
__device__ __forceinline__ void f_slartg(float f, float g, float* cs, float* sn, float* r) {
    if (g == 0.f) { *cs = 1.f; *sn = 0.f; *r = f; }
    else if (f == 0.f) { *cs = 0.f; *sn = copysignf(1.f, g); *r = fabsf(g); }
    else {
        float d = sqrtf(__fadd_rn(__fmul_rn(f, f), __fmul_rn(g, g)));
        *cs = fabsf(f) / d;
        *r  = copysignf(d, f);
        *sn = g / *r;
    }
}

__device__ void f_slaev2(float a, float b, float c,
                         float* rt1, float* rt2, float* cs1, float* sn1) {
    float sm = a + c;
    float df = a - c;
    float adf = fabsf(df);
    float tb = b + b;
    float ab = fabsf(tb);
    float acmx, acmn;
    if (fabsf(a) > fabsf(c)) { acmx = a; acmn = c; } else { acmx = c; acmn = a; }
    float rt;
    if (adf > ab)      { float q = ab / adf; rt = adf * sqrtf(1.f + q * q); }
    else if (adf < ab) { float q = adf / ab; rt = ab * sqrtf(1.f + q * q); }
    else               rt = ab * sqrtf(2.f);
    int sgn1;
    if (sm < 0.f) {
        *rt1 = 0.5f * (sm - rt); sgn1 = -1;
        *rt2 = (acmx / *rt1) * acmn - (b / *rt1) * b;
    } else if (sm > 0.f) {
        *rt1 = 0.5f * (sm + rt); sgn1 = 1;
        *rt2 = (acmx / *rt1) * acmn - (b / *rt1) * b;
    } else {
        *rt1 = 0.5f * rt; *rt2 = -0.5f * rt; sgn1 = 1;
    }
    float cs; int sgn2;
    if (df >= 0.f) { cs = df + rt; sgn2 = 1; }
    else           { cs = df - rt; sgn2 = -1; }
    float acs = fabsf(cs);
    if (acs > ab) {
        float ct = -tb / cs;
        *sn1 = 1.f / sqrtf(1.f + ct * ct);
        *cs1 = ct * *sn1;
    } else {
        if (ab == 0.f) { *cs1 = 1.f; *sn1 = 0.f; }
        else {
            float tn = -cs / tb;
            *cs1 = 1.f / sqrtf(1.f + tn * tn);
            *sn1 = tn * *cs1;
        }
    }
    if (sgn1 == sgn2) { float tn = *cs1; *cs1 = -*sn1; *sn1 = tn; }
}

// --------- register-resident dynamic indexing (R9: replaces scratch arrays) ---------
// Selection only — bit-exact with array loads/stores; compiles to v_cndmask, no memory.

__device__ __forceinline__ float get3(float a, float b, float c, int i) {
    return i == 0 ? a : (i == 1 ? b : c);
}
__device__ __forceinline__ void set3(float& a, float& b, float& c, int i, float v) {
    a = (i == 0) ? v : a;
    b = (i == 1) ? v : b;
    c = (i == 2) ? v : c;
}
__device__ __forceinline__ float get2(float a, float b, int i) { return i == 0 ? a : b; }
__device__ __forceinline__ void set2(float& a, float& b, int i, float v) {
    a = (i == 0) ? v : a;
    b = (i == 1) ? v : b;
}

#define DGET(i)    get3(dd0, dd1, dd2, (i))
#define DSET(i, v) set3(dd0, dd1, dd2, (i), (v))
#define EGET(i)    get2(ee0, ee1, (i))
#define ESET(i, v) set2(ee0, ee1, (i), (v))
#define ZGET(r, c)    get3(z##r##0, z##r##1, z##r##2, (c))
#define ZSET(r, c, v) set3(z##r##0, z##r##1, z##r##2, (c), (v))
// Two-column Givens update: cols (ca,cb) <- (cc*ca - ss*cb, ss*ca + cc*cb), all 3 rows.
#define ZROT(r, ca, cb, cc, ss) { float zt_ = ZGET(r, (ca)); float zb_ = ZGET(r, (cb)); \
    ZSET(r, (ca), (cc) * zt_ - (ss) * zb_); ZSET(r, (cb), (ss) * zt_ + (cc) * zb_); }
#define ZROT3(ca, cb, cc, ss) { ZROT(0, (ca), (cb), (cc), (ss)) ZROT(1, (ca), (cb), (cc), (ss)) ZROT(2, (ca), (cb), (cc), (ss)) }

// fp32 ssyevd for a 3x3 symmetric matrix (lower triangle given), returns
// eigenvector of the SMALLEST eigenvalue, with LAPACK's sign convention.
__device__ void ssyevd3_evec0(float a00, float a10, float a20,
                              float a11, float a21, float a22,
                              float* ox, float* oy, float* oz) {
    // ---- ssytd2('L') ----
    float dd0, dd1, dd2, ee0, ee1;
    float tau = 0.f, v2 = 0.f;
    float xnorm = fabsf(a20);
    if (xnorm == 0.f) {
        tau = 0.f;
        dd0 = a00; dd1 = a11; dd2 = a22; ee0 = a10; ee1 = a21;
    } else {
        float beta = -copysignf(f_slapy2(a10, xnorm), a10);
        tau = (beta - a10) / beta;
        float inv = 1.f / (a10 - beta);
        v2 = a20 * inv;
        float x1 = tau * (a11 + a21 * v2);
        float x2 = tau * (a21 + a22 * v2);
        float alpha = -0.5f * tau * (x1 + x2 * v2);
        float w1 = x1 + alpha;
        float w2 = x2 + alpha * v2;
        float b11 = a11 - 2.f * w1;
        float b21 = a21 - v2 * w1 - w2;
        float b22 = a22 - 2.f * (v2 * w2);
        dd0 = a00; dd1 = b11; dd2 = b22; ee0 = beta; ee1 = b21;
    }
    // ---- ssteqr('I', n=3) ----
    const float eps    = 5.9604645e-08f;
    const float eps2   = eps * eps;
    const float safmin = 1.1754944e-38f;
    const float ssfmax = sqrtf(1.f / safmin) / 3.f;
    const float ssfmin = sqrtf(safmin) / eps2;
    const int n = 3, nmaxit = 90;
    float z00 = 1.f, z01 = 0.f, z02 = 0.f;
    float z10 = 0.f, z11 = 1.f, z12 = 0.f;
    float z20 = 0.f, z21 = 0.f, z22 = 1.f;
    int jtot = 0;
    int l1 = 1;

    while (true) {
        if (l1 > n) break;
        if (l1 > 1) ESET(l1 - 2, 0.f);
        int m = n;
        {   // for (mi = l1; mi <= n-1; ++mi) with first-hit break
            bool found = false;
            #pragma unroll
            for (int mi = 1; mi <= 2; ++mi) {
                if (!found && mi >= l1) {
                    float tst = fabsf(EGET(mi - 1));
                    if (tst == 0.f) { m = mi; found = true; }
                    else if (tst <= (sqrtf(fabsf(DGET(mi - 1))) * sqrtf(fabsf(DGET(mi)))) * eps) {
                        ESET(mi - 1, 0.f); m = mi; found = true;
                    }
                }
            }
        }
        int l = l1, lsv = l, lend = m, lendsv = lend;
        l1 = m + 1;
        if (lend == l) continue;

        float anorm = 0.f;
        #pragma unroll
        for (int i = 1; i <= 3; ++i)
            if (i >= l && i <= lend) anorm = fmaxf(anorm, fabsf(DGET(i - 1)));
        #pragma unroll
        for (int i = 1; i <= 2; ++i)
            if (i >= l && i <= lend - 1) anorm = fmaxf(anorm, fabsf(EGET(i - 1)));
        int iscale = 0; float sclto = 1.f;
        if (anorm == 0.f) continue;
        if (anorm > ssfmax) { iscale = 1; sclto = ssfmax; }
        else if (anorm < ssfmin) { iscale = 2; sclto = ssfmin; }
        if (iscale) {
            float mul = sclto / anorm;
            #pragma unroll
            for (int i = 1; i <= 3; ++i)
                if (i >= l && i <= lend) DSET(i - 1, DGET(i - 1) * mul);
            #pragma unroll
            for (int i = 1; i <= 2; ++i)
                if (i >= l && i <= lend - 1) ESET(i - 1, EGET(i - 1) * mul);
        }
        if (fabsf(DGET(lend - 1)) < fabsf(DGET(l - 1))) { lend = lsv; l = lendsv; }

        if (lend > l) {
            // QL
            while (true) {
                int mq = lend;
                if (l != lend) {
                    bool found = false;
                    #pragma unroll
                    for (int i = 1; i <= 2; ++i) {
                        if (!found && i >= l && i <= lend - 1) {
                            float ei = EGET(i - 1);
                            float tst = ei * ei;
                            if (tst <= (eps2 * fabsf(DGET(i - 1))) * fabsf(DGET(i)) + safmin) { mq = i; found = true; }
                        }
                    }
                }
                if (mq < lend) ESET(mq - 1, 0.f);
                float p = DGET(l - 1);
                if (mq == l) { DSET(l - 1, p); l = l + 1; if (l <= lend) continue; break; }
                if (mq == l + 1) {
                    float rt1, rt2, c, s;
                    f_slaev2(DGET(l - 1), EGET(l - 1), DGET(l), &rt1, &rt2, &c, &s);
                    ZROT3(l, l - 1, c, s);
                    DSET(l - 1, rt1); DSET(l, rt2); ESET(l - 1, 0.f);
                    l += 2; if (l <= lend) continue; break;
                }
                if (jtot == nmaxit) break;
                jtot++;
                float g = (DGET(l) - p) / (2.f * EGET(l - 1));
                float r = f_slapy2(g, 1.f);
                g = DGET(mq - 1) - p + EGET(l - 1) / (g + copysignf(r, g));
                float s = 1.f, c = 1.f; p = 0.f;
                float cw0 = 0.f, cw1 = 0.f, sw0 = 0.f, sw1 = 0.f;
                // for (i = mq-1; i >= l; --i)
                #pragma unroll
                for (int i = 2; i >= 1; --i) {
                    if (i <= mq - 1 && i >= l) {
                        float f = s * EGET(i - 1);
                        float b = c * EGET(i - 1);
                        f_slartg(g, f, &c, &s, &r);
                        if (i != mq - 1) ESET(i, r);
                        g = DGET(i) - p;
                        r = (DGET(i - 1) - g) * s + 2.f * c * b;
                        p = s * r;
                        DSET(i, g + p);
                        g = c * r - b;
                        set2(cw0, cw1, i - l, c);
                        set2(sw0, sw1, i - l, -s);
                    }
                }
                // for (j = mq-l; j >= 1; --j)
                #pragma unroll
                for (int j = 2; j >= 1; --j) {
                    if (j <= mq - l) {
                        float cj = get2(cw0, cw1, j - 1), sj = get2(sw0, sw1, j - 1);
                        int c0 = l - 1 + (j - 1);
                        ZROT3(c0 + 1, c0, cj, sj);
                    }
                }
                DSET(l - 1, DGET(l - 1) - p);
                ESET(l - 1, g);
            }
        } else {
            // QR
            while (true) {
                int mq = lend;
                if (l != lend) {
                    bool found = false;
                    // for (i = l; i >= lend+1; --i)
                    #pragma unroll
                    for (int i = 3; i >= 2; --i) {
                        if (!found && i <= l && i >= lend + 1) {
                            float ei = EGET(i - 2);
                            float tst = ei * ei;
                            if (tst <= (eps2 * fabsf(DGET(i - 1))) * fabsf(DGET(i - 2)) + safmin) { mq = i; found = true; }
                        }
                    }
                }
                if (mq > lend) ESET(mq - 2, 0.f);
                float p = DGET(l - 1);
                if (mq == l) { DSET(l - 1, p); l = l - 1; if (l >= lend) continue; break; }
                if (mq == l - 1) {
                    float rt1, rt2, c, s;
                    f_slaev2(DGET(l - 2), EGET(l - 2), DGET(l - 1), &rt1, &rt2, &c, &s);
                    ZROT3(l - 1, l - 2, c, s);
                    DSET(l - 2, rt1); DSET(l - 1, rt2); ESET(l - 2, 0.f);
                    l -= 2; if (l >= lend) continue; break;
                }
                if (jtot == nmaxit) break;
                jtot++;
                float g = (DGET(l - 2) - p) / (2.f * EGET(l - 2));
                float r = f_slapy2(g, 1.f);
                g = DGET(mq - 1) - p + EGET(l - 2) / (g + copysignf(r, g));
                float s = 1.f, c = 1.f; p = 0.f;
                float cw0 = 0.f, cw1 = 0.f, sw0 = 0.f, sw1 = 0.f;
                // for (i = mq; i <= l-1; ++i)
                #pragma unroll
                for (int i = 1; i <= 2; ++i) {
                    if (i >= mq && i <= l - 1) {
                        float f = s * EGET(i - 1);
                        float b = c * EGET(i - 1);
                        f_slartg(g, f, &c, &s, &r);
                        if (i != mq) ESET(i - 2, r);
                        g = DGET(i - 1) - p;
                        r = (DGET(i) - g) * s + 2.f * c * b;
                        p = s * r;
                        DSET(i - 1, g + p);
                        g = c * r - b;
                        set2(cw0, cw1, i - mq, c);
                        set2(sw0, sw1, i - mq, s);
                    }
                }
                // for (j = 1; j <= l-mq; ++j)
                #pragma unroll
                for (int j = 1; j <= 2; ++j) {
                    if (j <= l - mq) {
                        float cj = get2(cw0, cw1, j - 1), sj = get2(sw0, sw1, j - 1);
                        int c0 = mq - 1 + (j - 1);
                        ZROT3(c0 + 1, c0, cj, sj);
                    }
                }
                DSET(l - 1, DGET(l - 1) - p);
                ESET(l - 2, g);
            }
        }
        if (iscale) {
            float mul = anorm / sclto;
            #pragma unroll
            for (int i = 1; i <= 3; ++i)
                if (i >= lsv && i <= lendsv) DSET(i - 1, DGET(i - 1) * mul);
            #pragma unroll
            for (int i = 1; i <= 2; ++i)
                if (i >= lsv && i <= lendsv - 1) ESET(i - 1, EGET(i - 1) * mul);
        }
        if (jtot >= nmaxit) break;
    }

    // sort ascending (column swaps — no sign change)
    #pragma unroll
    for (int ii = 2; ii <= 3; ++ii) {
        int i = ii - 1, k = i;
        float p = DGET(i - 1);
        #pragma unroll
        for (int j = ii; j <= 3; ++j)
            if (DGET(j - 1) < p) { k = j; p = DGET(j - 1); }
        if (k != i) {
            DSET(k - 1, DGET(i - 1)); DSET(i - 1, p);
            { float t0 = ZGET(0, i - 1); ZSET(0, i - 1, ZGET(0, k - 1)); ZSET(0, k - 1, t0); }
            { float t1 = ZGET(1, i - 1); ZSET(1, i - 1, ZGET(1, k - 1)); ZSET(1, k - 1, t1); }
            { float t2 = ZGET(2, i - 1); ZSET(2, i - 1, ZGET(2, k - 1)); ZSET(2, k - 1, t2); }
        }
    }
    // sormtr('L','L','N')
    float r0 = z00, r1 = z10, r2 = z20;
    if (tau != 0.f) {
        float sum = r1 + v2 * r2;
        r1 -= tau * sum;
        r2 -= tau * (v2 * sum);
    }
    *ox = r0; *oy = r1; *oz = r2;
}

// ---------------- common ----------------

__device__ __forceinline__ float dot_rn(float ax, float ay, float az,
                                        float bx, float by, float bz) {
    return __fadd_rn(__fadd_rn(__fmul_rn(ax, bx), __fmul_rn(ay, by)), __fmul_rn(az, bz));
}

// Branchless sorted-chain inserts: keys ascending; drops the largest.
__device__ __forceinline__ void chain10(unsigned k[KW], unsigned x) {
    unsigned t = x;
    #pragma unroll
    for (int s = 0; s < KW; ++s) {
        unsigned lo = k[s] < t ? k[s] : t;
        unsigned hi = k[s] < t ? t : k[s];
        k[s] = lo; t = hi;
    }
}
__device__ __forceinline__ void chain16(unsigned k[KN], unsigned x) {
    unsigned t = x;
    #pragma unroll
    for (int s = 0; s < KN; ++s) {
        unsigned lo = k[s] < t ? k[s] : t;
        unsigned hi = k[s] < t ? t : k[s];
        k[s] = lo; t = hi;
    }
}

// ---------------- fused scan + 8-way-parallel tail ----------------
// 512 blocks x 512 threads (8 waves), 2 blocks/CU (64KB LDS). Normal launch.
// Phase 1 (scan): wave w scans interleaved slice j=8t+w, branchless sorted top-10
//   per lane-query + chamfer partial min. Publish to LDS.
// Phase 2 (tail, ALL 8 waves): wave w handles queries q = w*8 + lane (lanes 0-7):
//   merge 8x10 -> exact top-16 (insert-order identical to R10), violation-detect
//   + rare rescan, repulsion, covariance from sHome, in-register ssyevd, normal
//   store (nP or nG). Per-block cd/rep partial -> cdpart[bi] (plain store).
#define KIDX(s, w, l) (((s) * 8 + (w)) * 64 + (l))

__global__ __launch_bounds__(512, 4) void scan_kernel(
    const float* __restrict__ pred, const float* __restrict__ gt,
    float* __restrict__ nP, float* __restrict__ nG,
    double* __restrict__ cdpart)
{
    __shared__ float4 sHome[NP];            // (x,y,z,|p|^2)  32 KB — stays live (fallback + gather)
    __shared__ float4 sOther[NP];           // (x,y,z,0)      32 KB — aliased post-scan
    unsigned* kbuf = (unsigned*)sOther;                       // [10][8][64] u32 = 20 KB
    float* mbuf = (float*)((char*)sOther + 20480);            // [8][64] f32 = 2 KB
    double* wsum = (double*)((char*)sOther + 22528);          // [8] f64 = 64 B

    int bi = blockIdx.x;
    bool predHome = bi < NB * 32;
    int lb = predHome ? bi : bi - NB * 32;
    int b = lb >> 5;
    int tile = lb & 31;
    int tid  = threadIdx.x;
    int wave = tid >> 6;
    int lane = tid & 63;

    const float* home  = (predHome ? pred : gt) + (size_t)b * NP * 3;
    const float* other = (predHome ? gt : pred) + (size_t)b * NP * 3;

    for (int t = tid; t < NP; t += 512) {
        float hx = home[3 * t], hy = home[3 * t + 1], hz = home[3 * t + 2];
        sHome[t] = make_float4(hx, hy, hz, dot_rn(hx, hy, hz, hx, hy, hz));
        float ox = other[3 * t], oy = other[3 * t + 1], oz = other[3 * t + 2];
        sOther[t] = make_float4(ox, oy, oz, 0.f);
    }
    __syncthreads();

    int im = tile * 64 + lane;              // original index of this lane's scan query
    float4 qv = sHome[im];
    float qx = qv.x, qy = qv.y, qz = qv.z, qq = qv.w;

    unsigned keys[KW];
    #pragma unroll
    for (int s = 0; s < KW; ++s) keys[s] = 0x7F800000u | (unsigned)s;  // sorted inf seeds

    float minv = 1e30f;

    for (int t = 0; t < NP / 8; ++t) {
        int jj = (t << 3) | wave;
        float4 h = sHome[jj];                                  // broadcast b128
        float dotj = dot_rn(qx, qy, qz, h.x, h.y, h.z);
        float d2 = __fsub_rn(__fadd_rn(qq, h.w), __fmul_rn(2.f, dotj));
        chain10(keys, (__float_as_uint(d2) & 0xFFFFF800u) | (unsigned)jj);
        float4 o = sOther[jj];                                 // broadcast b128
        float ex = qx - o.x, ey = qy - o.y, ez = qz - o.z;
        minv = fminf(minv, fmaf(ex, ex, fmaf(ey, ey, ez * ez)));
    }
    __syncthreads();   // all sOther reads done before kbuf aliasing writes

    // publish per-wave sorted top-10 + chamfer partial min
    #pragma unroll
    for (int s = 0; s < KW; ++s) kbuf[KIDX(s, wave, lane)] = keys[s];
    mbuf[wave * 64 + lane] = minv;
    __syncthreads();

    // ---------------- tail: all 8 waves, 8 queries each on lanes 0-7 ----------------
    double wavepart = 0.0;
    if (lane < 8) {
        int q = wave * 8 + lane;            // query-lane 0..63
        int imq = tile * 64 + q;
        float4 qp = sHome[imq];
        float tqx = qp.x, tqy = qp.y, tqz = qp.z, tqq = qp.w;

        // --- merge 8x10 -> sorted top-16 (insert sequence identical to R10) ---
        unsigned k16[KN];
        #pragma unroll
        for (int s = 0; s < KW; ++s) k16[s] = kbuf[KIDX(s, 0, q)];   // wave-0's sorted 10
        #pragma unroll
        for (int s = KW; s < KN; ++s) k16[s] = 0x7F800000u | (unsigned)s;  // seeds (> any real)
        for (int w = 1; w < 8; ++w) {
            #pragma unroll
            for (int s = 0; s < KW; ++s) chain16(k16, kbuf[KIDX(s, w, q)]);
        }
        float qminv = fminf(fminf(fminf(mbuf[q], mbuf[64 + q]),
                                  fminf(mbuf[128 + q], mbuf[192 + q])),
                            fminf(fminf(mbuf[256 + q], mbuf[320 + q]),
                                  fminf(mbuf[384 + q], mbuf[448 + q])));

        // --- violation detect: slice may hide a top-16 member iff its 10th-best
        //     (kbuf slot 9, sorted) < pool 16th (k16[15]). Exact repair below. ---
        unsigned flags = 0;
        #pragma unroll
        for (int w = 0; w < 8; ++w)
            flags |= (kbuf[KIDX(KW - 1, w, q)] < k16[15]) ? (1u << w) : 0u;

        if (__any(flags != 0)) {                 // ~0.07 expected events per LAUNCH
            #pragma unroll
            for (int s = 0; s < KN; ++s)
                k16[s] = flags ? (0x7F800000u | (unsigned)s) : k16[s];   // reinit flagged lanes
            for (int w = 0; w < 8; ++w) {
                #pragma unroll
                for (int s = 0; s < KW; ++s) {
                    unsigned kk = kbuf[KIDX(s, w, q)];
                    bool use = (flags != 0) && !((flags >> w) & 1);
                    chain16(k16, use ? kk : 0xFFFFFFFFu);          // inf = no-op
                }
            }
            for (int w = 0; w < 8; ++w) {
                if (__any((flags >> w) & 1)) {
                    bool actw = ((flags >> w) & 1) != 0;
                    for (int t = 0; t < NP / 8; ++t) {
                        int jj = (t << 3) | w;
                        float4 h = sHome[jj];
                        float dotj = dot_rn(tqx, tqy, tqz, h.x, h.y, h.z);
                        float d2 = __fsub_rn(__fadd_rn(tqq, h.w), __fmul_rn(2.f, dotj));
                        unsigned key = (__float_as_uint(d2) & 0xFFFFF800u) | (unsigned)jj;
                        chain16(k16, actw ? key : 0xFFFFFFFFu);
                    }
                }
            }
        }

        // --- repulsion: k16 sorted ascending, slot 0 = self (d2=0) -> slots 1..4 ---
        float rep = 0.0f;
        if (predHome) {
            #pragma unroll
            for (int r = 1; r <= 4; ++r) {
                float d2 = __uint_as_float(k16[r] & 0xFFFFF800u);
                float dd = sqrtf(fmaxf(d2, 1e-12f));
                rep += fmaxf(0.02f - dd, 0.0f);
            }
        }

        // --- covariance over the 16-NN: gather from sHome (bit-identical values) ---
        float sx = 0.f, sy = 0.f, sz = 0.f;
        #pragma unroll
        for (int s = 0; s < KN; ++s) {
            float4 p = sHome[k16[s] & 0x7FFu];
            sx += p.x; sy += p.y; sz += p.z;
        }
        float mx = sx * (1.0f / KN), my = sy * (1.0f / KN), mz = sz * (1.0f / KN);
        float cxx = 0.f, cxy = 0.f, cxz = 0.f, cyy = 0.f, cyz = 0.f, czz = 0.f;
        #pragma unroll
        for (int s = 0; s < KN; ++s) {
            float4 p = sHome[k16[s] & 0x7FFu];
            float ax = p.x - mx;
            float ay = p.y - my;
            float az = p.z - mz;
            cxx += ax * ax; cxy += ax * ay; cxz += ax * az;
            cyy += ay * ay; cyz += ay * az; czz += az * az;
        }
        cxx *= (1.f / KN); cxy *= (1.f / KN); cxz *= (1.f / KN);
        cyy *= (1.f / KN); cyz *= (1.f / KN); czz *= (1.f / KN);

        // --- normal via faithful ssyevd emulation (register-resident) ---
        float nx, ny, nz;
        ssyevd3_evec0(cxx, cxy, cxz, cyy, cyz, czz, &nx, &ny, &nz);

        float* nout = predHome ? nP : nG;
        int gi = b * NP + imq;
        nout[gi * 3 + 0] = nx;
        nout[gi * 3 + 1] = ny;
        nout[gi * 3 + 2] = nz;

        wavepart = (double)qminv * (1.0 / (NB * NP))
                 + (double)rep   * (0.1 / (NB * NP * 4));
    }

    // reduce the 8 per-query parts within the wave (lanes >=8 hold 0)
    #pragma unroll
    for (int off = 4; off > 0; off >>= 1) wavepart += __shfl_down(wavepart, off);
    if (lane == 0) wsum[wave] = wavepart;
    __syncthreads();
    if (tid == 0) {
        double t = 0.0;
        #pragma unroll
        for (int w = 0; w < 8; ++w) t += wsum[w];
        cdpart[bi] = t;
    }
}

// ---------------------------------------------------------------------------
// Normal-dot partials: 16 blocks x 64 threads = the same 1024 virtual threads /
// fp32 summation order as R10's passing dot_kernel; plain-stores dotpart[bid].
__global__ __launch_bounds__(64) void dot_kernel(
    const float* __restrict__ nP, const float* __restrict__ nG,
    double* __restrict__ dotpart)
{
    int vt = blockIdx.x * 64 + threadIdx.x;   // 0..1023
    float s = 0.f;
    for (int i = vt; i < NB * NP; i += 1024)
        s += nP[3 * i] * nG[3 * i] + nP[3 * i + 1] * nG[3 * i + 1] + nP[3 * i + 2] * nG[3 * i + 2];
    double part = (double)s;
    #pragma unroll
    for (int off = 32; off > 0; off >>= 1) part += __shfl_down(part, off);
    if (threadIdx.x == 0) dotpart[blockIdx.x] = part;
}

// ---------------------------------------------------------------------------
// Finalize: 1 block x 512. Reduce 512 cdpart + 16 dotpart (doubles), write out.
__global__ __launch_bounds__(512) void fin_kernel(
    const double* __restrict__ cdpart, const double* __restrict__ dotpart,
    float* __restrict__ out)
{
    __shared__ double wc[8], wd[8];
    int tid = threadIdx.x;
    int wave = tid >> 6, lane = tid & 63;
    double c = cdpart[tid];                              // 512 slots
    double d = (tid < 16) ? dotpart[tid] : 0.0;          // 16 slots
    #pragma unroll
    for (int off = 32; off > 0; off >>= 1) {
        c += __shfl_down(c, off);
        d += __shfl_down(d, off);
    }
    if (lane == 0) { wc[wave] = c; wd[wave] = d; }
    __syncthreads();
    if (tid == 0) {
        double a = 0.0, t = 0.0;
        #pragma unroll
        for (int w = 0; w < 8; ++w) { a += wc[w]; t += wd[w]; }
        out[0] = (float)(a - t * (0.01 / (NB * NP)) + 0.01);
    }
}

// ---------------------------------------------------------------------------
extern "C" void kernel_launch(void* const* d_in, const int* in_sizes, int n_in,
                              void* d_out, int out_size, void* d_ws, size_t ws_size,
                              hipStream_t stream)
{
    const float* pred = (const float*)d_in[0];
    const float* gt   = (const float*)d_in[1];

    // ws layout: nP (192KB) | nG (192KB) | cdpart (512 f64 = 4KB) | dotpart (16 f64).
    // No memset needed: every slot is written before being read (stream order).
    char* base = (char*)d_ws;
    float*  nP      = (float*)base;
    float*  nG      = nP + (size_t)NB * NP * 3;
    double* cdpart  = (double*)(nG + (size_t)NB * NP * 3);
    double* dotpart = cdpart + 512;

    scan_kernel<<<dim3(NB * 32 * 2), dim3(512), 0, stream>>>(pred, gt, nP, nG, cdpart);
    dot_kernel<<<dim3(16), dim3(64), 0, stream>>>(nP, nG, dotpart);
    fin_kernel<<<dim3(1), dim3(512), 0, stream>>>(cdpart, dotpart, (float*)d_out);
}

// Round 6
// 162.334 us; speedup vs baseline: 1.2045x; 1.2045x over previous
//
#include <hip/hip_runtime.h>

// CombinedLoss: chamfer(pred,gt) + 0.1*repulsion(pred,k=4) + 0.01*(1 - mean(n_pred . n_gt))
// B=8, N=2048, fp32 in, fp32 scalar out.
// Normals match np.linalg.eigh (LAPACK ssyevd) signs point-by-point via faithful
// fp32 ssytd2+ssteqr+sormtr emulation (R3-R7: absmax 0.0).
// R8: branchless sorted-chain top-10 per wave-slice, exact top-16 via 8x10 pool
// merge + violation-detect + rare rescan fallback.
// R9: eigensolver state in named registers (cndmask dynamic indexing).
// R10: split kernels -> ~10us/launch x5 ate the win.
// R11/R12: hipLaunchCooperativeKernel NOT executed by harness graph capture.
// R13: 8-way tail on lanes 0-7 REGRESSED scan 95->155us. LESSON: exec-masked
// lanes still consume VALU issue slots (wave64 op = 2cy regardless of active
// lanes); 8 waves x 8-lane tail = 8x the issue work of one packed wave.
// R14: tail reverted to R9's FULL-PACK form (wave 0, 64 lanes = 64 queries,
// merge+cov+eig inline, bit-exact insert order); dot+fin collapsed into ONE
// 1-block x 1024-thread kernel (dot per-thread fp32 order identical to the
// passing dot_kernel: vt=tid, stride 1024; only double-combine order differs,
// ~1e-16 relative). 2 launches total, no memset, no atomics.

#define NB 8
#define NP 2048
#define KW 10     // per-slice kept keys
#define KN 16

// ---------------- LAPACK helpers (fp32, faithful — DO NOT TOUCH) ----------------

__device__ __forceinline__ float f_slapy2(float x, float y) {
    float xa = fabsf(x), ya = fabsf(y);
    float w = fmaxf(xa, ya), zm = fminf(xa, ya);
    if (zm == 0.f) return w;
    float q = zm / w;
    return w * sqrtf(1.f + q * q);
}

// LAPACK >=3.10 slartg convention: c >= 0 always.
__device__ __forceinline__ void f_slartg(float f, float g, float* cs, float* sn, float* r) {
    if (g == 0.f) { *cs = 1.f; *sn = 0.f; *r = f; }
    else if (f == 0.f) { *cs = 0.f; *sn = copysignf(1.f, g); *r = fabsf(g); }
    else {
        float d = sqrtf(__fadd_rn(__fmul_rn(f, f), __fmul_rn(g, g)));
        *cs = fabsf(f) / d;
        *r  = copysignf(d, f);
        *sn = g / *r;
    }
}

__device__ void f_slaev2(float a, float b, float c,
                         float* rt1, float* rt2, float* cs1, float* sn1) {
    float sm = a + c;
    float df = a - c;
    float adf = fabsf(df);
    float tb = b + b;
    float ab = fabsf(tb);
    float acmx, acmn;
    if (fabsf(a) > fabsf(c)) { acmx = a; acmn = c; } else { acmx = c; acmn = a; }
    float rt;
    if (adf > ab)      { float q = ab / adf; rt = adf * sqrtf(1.f + q * q); }
    else if (adf < ab) { float q = adf / ab; rt = ab * sqrtf(1.f + q * q); }
    else               rt = ab * sqrtf(2.f);
    int sgn1;
    if (sm < 0.f) {
        *rt1 = 0.5f * (sm - rt); sgn1 = -1;
        *rt2 = (acmx / *rt1) * acmn - (b / *rt1) * b;
    } else if (sm > 0.f) {
        *rt1 = 0.5f * (sm + rt); sgn1 = 1;
        *rt2 = (acmx / *rt1) * acmn - (b / *rt1) * b;
    } else {
        *rt1 = 0.5f * rt; *rt2 = -0.5f * rt; sgn1 = 1;
    }
    float cs; int sgn2;
    if (df >= 0.f) { cs = df + rt; sgn2 = 1; }
    else           { cs = df - rt; sgn2 = -1; }
    float acs = fabsf(cs);
    if (acs > ab) {
        float ct = -tb / cs;
        *sn1 = 1.f / sqrtf(1.f + ct * ct);
        *cs1 = ct * *sn1;
    } else {
        if (ab == 0.f) { *cs1 = 1.f; *sn1 = 0.f; }
        else {
            float tn = -cs / tb;
            *cs1 = 1.f / sqrtf(1.f + tn * tn);
            *sn1 = tn * *cs1;
        }
    }
    if (sgn1 == sgn2) { float tn = *cs1; *cs1 = -*sn1; *sn1 = tn; }
}

// --------- register-resident dynamic indexing (R9: replaces scratch arrays) ---------
// Selection only — bit-exact with array loads/stores; compiles to v_cndmask, no memory.

__device__ __forceinline__ float get3(float a, float b, float c, int i) {
    return i == 0 ? a : (i == 1 ? b : c);
}
__device__ __forceinline__ void set3(float& a, float& b, float& c, int i, float v) {
    a = (i == 0) ? v : a;
    b = (i == 1) ? v : b;
    c = (i == 2) ? v : c;
}
__device__ __forceinline__ float get2(float a, float b, int i) { return i == 0 ? a : b; }
__device__ __forceinline__ void set2(float& a, float& b, int i, float v) {
    a = (i == 0) ? v : a;
    b = (i == 1) ? v : b;
}

#define DGET(i)    get3(dd0, dd1, dd2, (i))
#define DSET(i, v) set3(dd0, dd1, dd2, (i), (v))
#define EGET(i)    get2(ee0, ee1, (i))
#define ESET(i, v) set2(ee0, ee1, (i), (v))
#define ZGET(r, c)    get3(z##r##0, z##r##1, z##r##2, (c))
#define ZSET(r, c, v) set3(z##r##0, z##r##1, z##r##2, (c), (v))
// Two-column Givens update: cols (ca,cb) <- (cc*ca - ss*cb, ss*ca + cc*cb), all 3 rows.
#define ZROT(r, ca, cb, cc, ss) { float zt_ = ZGET(r, (ca)); float zb_ = ZGET(r, (cb)); \
    ZSET(r, (ca), (cc) * zt_ - (ss) * zb_); ZSET(r, (cb), (ss) * zt_ + (cc) * zb_); }
#define ZROT3(ca, cb, cc, ss) { ZROT(0, (ca), (cb), (cc), (ss)) ZROT(1, (ca), (cb), (cc), (ss)) ZROT(2, (ca), (cb), (cc), (ss)) }

// fp32 ssyevd for a 3x3 symmetric matrix (lower triangle given), returns
// eigenvector of the SMALLEST eigenvalue, with LAPACK's sign convention.
__device__ void ssyevd3_evec0(float a00, float a10, float a20,
                              float a11, float a21, float a22,
                              float* ox, float* oy, float* oz) {
    // ---- ssytd2('L') ----
    float dd0, dd1, dd2, ee0, ee1;
    float tau = 0.f, v2 = 0.f;
    float xnorm = fabsf(a20);
    if (xnorm == 0.f) {
        tau = 0.f;
        dd0 = a00; dd1 = a11; dd2 = a22; ee0 = a10; ee1 = a21;
    } else {
        float beta = -copysignf(f_slapy2(a10, xnorm), a10);
        tau = (beta - a10) / beta;
        float inv = 1.f / (a10 - beta);
        v2 = a20 * inv;
        float x1 = tau * (a11 + a21 * v2);
        float x2 = tau * (a21 + a22 * v2);
        float alpha = -0.5f * tau * (x1 + x2 * v2);
        float w1 = x1 + alpha;
        float w2 = x2 + alpha * v2;
        float b11 = a11 - 2.f * w1;
        float b21 = a21 - v2 * w1 - w2;
        float b22 = a22 - 2.f * (v2 * w2);
        dd0 = a00; dd1 = b11; dd2 = b22; ee0 = beta; ee1 = b21;
    }
    // ---- ssteqr('I', n=3) ----
    const float eps    = 5.9604645e-08f;
    const float eps2   = eps * eps;
    const float safmin = 1.1754944e-38f;
    const float ssfmax = sqrtf(1.f / safmin) / 3.f;
    const float ssfmin = sqrtf(safmin) / eps2;
    const int n = 3, nmaxit = 90;
    float z00 = 1.f, z01 = 0.f, z02 = 0.f;
    float z10 = 0.f, z11 = 1.f, z12 = 0.f;
    float z20 = 0.f, z21 = 0.f, z22 = 1.f;
    int jtot = 0;
    int l1 = 1;

    while (true) {
        if (l1 > n) break;
        if (l1 > 1) ESET(l1 - 2, 0.f);
        int m = n;
        {   // for (mi = l1; mi <= n-1; ++mi) with first-hit break
            bool found = false;
            #pragma unroll
            for (int mi = 1; mi <= 2; ++mi) {
                if (!found && mi >= l1) {
                    float tst = fabsf(EGET(mi - 1));
                    if (tst == 0.f) { m = mi; found = true; }
                    else if (tst <= (sqrtf(fabsf(DGET(mi - 1))) * sqrtf(fabsf(DGET(mi)))) * eps) {
                        ESET(mi - 1, 0.f); m = mi; found = true;
                    }
                }
            }
        }
        int l = l1, lsv = l, lend = m, lendsv = lend;
        l1 = m + 1;
        if (lend == l) continue;

        float anorm = 0.f;
        #pragma unroll
        for (int i = 1; i <= 3; ++i)
            if (i >= l && i <= lend) anorm = fmaxf(anorm, fabsf(DGET(i - 1)));
        #pragma unroll
        for (int i = 1; i <= 2; ++i)
            if (i >= l && i <= lend - 1) anorm = fmaxf(anorm, fabsf(EGET(i - 1)));
        int iscale = 0; float sclto = 1.f;
        if (anorm == 0.f) continue;
        if (anorm > ssfmax) { iscale = 1; sclto = ssfmax; }
        else if (anorm < ssfmin) { iscale = 2; sclto = ssfmin; }
        if (iscale) {
            float mul = sclto / anorm;
            #pragma unroll
            for (int i = 1; i <= 3; ++i)
                if (i >= l && i <= lend) DSET(i - 1, DGET(i - 1) * mul);
            #pragma unroll
            for (int i = 1; i <= 2; ++i)
                if (i >= l && i <= lend - 1) ESET(i - 1, EGET(i - 1) * mul);
        }
        if (fabsf(DGET(lend - 1)) < fabsf(DGET(l - 1))) { lend = lsv; l = lendsv; }

        if (lend > l) {
            // QL
            while (true) {
                int mq = lend;
                if (l != lend) {
                    bool found = false;
                    #pragma unroll
                    for (int i = 1; i <= 2; ++i) {
                        if (!found && i >= l && i <= lend - 1) {
                            float ei = EGET(i - 1);
                            float tst = ei * ei;
                            if (tst <= (eps2 * fabsf(DGET(i - 1))) * fabsf(DGET(i)) + safmin) { mq = i; found = true; }
                        }
                    }
                }
                if (mq < lend) ESET(mq - 1, 0.f);
                float p = DGET(l - 1);
                if (mq == l) { DSET(l - 1, p); l = l + 1; if (l <= lend) continue; break; }
                if (mq == l + 1) {
                    float rt1, rt2, c, s;
                    f_slaev2(DGET(l - 1), EGET(l - 1), DGET(l), &rt1, &rt2, &c, &s);
                    ZROT3(l, l - 1, c, s);
                    DSET(l - 1, rt1); DSET(l, rt2); ESET(l - 1, 0.f);
                    l += 2; if (l <= lend) continue; break;
                }
                if (jtot == nmaxit) break;
                jtot++;
                float g = (DGET(l) - p) / (2.f * EGET(l - 1));
                float r = f_slapy2(g, 1.f);
                g = DGET(mq - 1) - p + EGET(l - 1) / (g + copysignf(r, g));
                float s = 1.f, c = 1.f; p = 0.f;
                float cw0 = 0.f, cw1 = 0.f, sw0 = 0.f, sw1 = 0.f;
                // for (i = mq-1; i >= l; --i)
                #pragma unroll
                for (int i = 2; i >= 1; --i) {
                    if (i <= mq - 1 && i >= l) {
                        float f = s * EGET(i - 1);
                        float b = c * EGET(i - 1);
                        f_slartg(g, f, &c, &s, &r);
                        if (i != mq - 1) ESET(i, r);
                        g = DGET(i) - p;
                        r = (DGET(i - 1) - g) * s + 2.f * c * b;
                        p = s * r;
                        DSET(i, g + p);
                        g = c * r - b;
                        set2(cw0, cw1, i - l, c);
                        set2(sw0, sw1, i - l, -s);
                    }
                }
                // for (j = mq-l; j >= 1; --j)
                #pragma unroll
                for (int j = 2; j >= 1; --j) {
                    if (j <= mq - l) {
                        float cj = get2(cw0, cw1, j - 1), sj = get2(sw0, sw1, j - 1);
                        int c0 = l - 1 + (j - 1);
                        ZROT3(c0 + 1, c0, cj, sj);
                    }
                }
                DSET(l - 1, DGET(l - 1) - p);
                ESET(l - 1, g);
            }
        } else {
            // QR
            while (true) {
                int mq = lend;
                if (l != lend) {
                    bool found = false;
                    // for (i = l; i >= lend+1; --i)
                    #pragma unroll
                    for (int i = 3; i >= 2; --i) {
                        if (!found && i <= l && i >= lend + 1) {
                            float ei = EGET(i - 2);
                            float tst = ei * ei;
                            if (tst <= (eps2 * fabsf(DGET(i - 1))) * fabsf(DGET(i - 2)) + safmin) { mq = i; found = true; }
                        }
                    }
                }
                if (mq > lend) ESET(mq - 2, 0.f);
                float p = DGET(l - 1);
                if (mq == l) { DSET(l - 1, p); l = l - 1; if (l >= lend) continue; break; }
                if (mq == l - 1) {
                    float rt1, rt2, c, s;
                    f_slaev2(DGET(l - 2), EGET(l - 2), DGET(l - 1), &rt1, &rt2, &c, &s);
                    ZROT3(l - 1, l - 2, c, s);
                    DSET(l - 2, rt1); DSET(l - 1, rt2); ESET(l - 2, 0.f);
                    l -= 2; if (l >= lend) continue; break;
                }
                if (jtot == nmaxit) break;
                jtot++;
                float g = (DGET(l - 2) - p) / (2.f * EGET(l - 2));
                float r = f_slapy2(g, 1.f);
                g = DGET(mq - 1) - p + EGET(l - 2) / (g + copysignf(r, g));
                float s = 1.f, c = 1.f; p = 0.f;
                float cw0 = 0.f, cw1 = 0.f, sw0 = 0.f, sw1 = 0.f;
                // for (i = mq; i <= l-1; ++i)
                #pragma unroll
                for (int i = 1; i <= 2; ++i) {
                    if (i >= mq && i <= l - 1) {
                        float f = s * EGET(i - 1);
                        float b = c * EGET(i - 1);
                        f_slartg(g, f, &c, &s, &r);
                        if (i != mq) ESET(i - 2, r);
                        g = DGET(i - 1) - p;
                        r = (DGET(i) - g) * s + 2.f * c * b;
                        p = s * r;
                        DSET(i - 1, g + p);
                        g = c * r - b;
                        set2(cw0, cw1, i - mq, c);
                        set2(sw0, sw1, i - mq, s);
                    }
                }
                // for (j = 1; j <= l-mq; ++j)
                #pragma unroll
                for (int j = 1; j <= 2; ++j) {
                    if (j <= l - mq) {
                        float cj = get2(cw0, cw1, j - 1), sj = get2(sw0, sw1, j - 1);
                        int c0 = mq - 1 + (j - 1);
                        ZROT3(c0 + 1, c0, cj, sj);
                    }
                }
                DSET(l - 1, DGET(l - 1) - p);
                ESET(l - 2, g);
            }
        }
        if (iscale) {
            float mul = anorm / sclto;
            #pragma unroll
            for (int i = 1; i <= 3; ++i)
                if (i >= lsv && i <= lendsv) DSET(i - 1, DGET(i - 1) * mul);
            #pragma unroll
            for (int i = 1; i <= 2; ++i)
                if (i >= lsv && i <= lendsv - 1) ESET(i - 1, EGET(i - 1) * mul);
        }
        if (jtot >= nmaxit) break;
    }

    // sort ascending (column swaps — no sign change)
    #pragma unroll
    for (int ii = 2; ii <= 3; ++ii) {
        int i = ii - 1, k = i;
        float p = DGET(i - 1);
        #pragma unroll
        for (int j = ii; j <= 3; ++j)
            if (DGET(j - 1) < p) { k = j; p = DGET(j - 1); }
        if (k != i) {
            DSET(k - 1, DGET(i - 1)); DSET(i - 1, p);
            { float t0 = ZGET(0, i - 1); ZSET(0, i - 1, ZGET(0, k - 1)); ZSET(0, k - 1, t0); }
            { float t1 = ZGET(1, i - 1); ZSET(1, i - 1, ZGET(1, k - 1)); ZSET(1, k - 1, t1); }
            { float t2 = ZGET(2, i - 1); ZSET(2, i - 1, ZGET(2, k - 1)); ZSET(2, k - 1, t2); }
        }
    }
    // sormtr('L','L','N')
    float r0 = z00, r1 = z10, r2 = z20;
    if (tau != 0.f) {
        float sum = r1 + v2 * r2;
        r1 -= tau * sum;
        r2 -= tau * (v2 * sum);
    }
    *ox = r0; *oy = r1; *oz = r2;
}

// ---------------- common ----------------

__device__ __forceinline__ float dot_rn(float ax, float ay, float az,
                                        float bx, float by, float bz) {
    return __fadd_rn(__fadd_rn(__fmul_rn(ax, bx), __fmul_rn(ay, by)), __fmul_rn(az, bz));
}

// Branchless sorted-chain inserts: keys ascending; drops the largest.
__device__ __forceinline__ void chain10(unsigned k[KW], unsigned x) {
    unsigned t = x;
    #pragma unroll
    for (int s = 0; s < KW; ++s) {
        unsigned lo = k[s] < t ? k[s] : t;
        unsigned hi = k[s] < t ? t : k[s];
        k[s] = lo; t = hi;
    }
}
__device__ __forceinline__ void chain16(unsigned k[KN], unsigned x) {
    unsigned t = x;
    #pragma unroll
    for (int s = 0; s < KN; ++s) {
        unsigned lo = k[s] < t ? k[s] : t;
        unsigned hi = k[s] < t ? t : k[s];
        k[s] = lo; t = hi;
    }
}

// ---------------- scan kernel (R9 tail structure) ----------------
// 512 blocks x 512 threads (8 waves), 2 blocks/CU (64KB LDS).
// Phase 1 (scan): wave w scans interleaved slice j=8t+w, branchless sorted top-10
//   per lane-query + chamfer partial min. Publish to LDS.
// Phase 2 (tail): wave 0 ONLY, fully packed: 64 lanes = 64 queries. Merge 8x10 ->
//   exact top-16 (+ violation rescan), repulsion, covariance from sHome,
//   in-register ssyevd, normal store. Block cd/rep partial -> cdpart[bi].
#define KIDX(s, w, l) (((s) * 8 + (w)) * 64 + (l))

__global__ __launch_bounds__(512, 4) void scan_kernel(
    const float* __restrict__ pred, const float* __restrict__ gt,
    float* __restrict__ nP, float* __restrict__ nG,
    double* __restrict__ cdpart)
{
    __shared__ float4 sHome[NP];            // (x,y,z,|p|^2)  32 KB — stays live (fallback + gather)
    __shared__ float4 sOther[NP];           // (x,y,z,0)      32 KB — aliased post-scan
    unsigned* kbuf = (unsigned*)sOther;                       // [10][8][64] u32 = 20 KB
    float* mbuf = (float*)((char*)sOther + 20480);            // [8][64] f32 = 2 KB

    int bi = blockIdx.x;
    bool predHome = bi < NB * 32;
    int lb = predHome ? bi : bi - NB * 32;
    int b = lb >> 5;
    int tile = lb & 31;
    int tid  = threadIdx.x;
    int wave = tid >> 6;
    int lane = tid & 63;

    const float* home  = (predHome ? pred : gt) + (size_t)b * NP * 3;
    const float* other = (predHome ? gt : pred) + (size_t)b * NP * 3;

    for (int t = tid; t < NP; t += 512) {
        float hx = home[3 * t], hy = home[3 * t + 1], hz = home[3 * t + 2];
        sHome[t] = make_float4(hx, hy, hz, dot_rn(hx, hy, hz, hx, hy, hz));
        float ox = other[3 * t], oy = other[3 * t + 1], oz = other[3 * t + 2];
        sOther[t] = make_float4(ox, oy, oz, 0.f);
    }
    __syncthreads();

    int im = tile * 64 + lane;              // original index of this lane's query
    float4 qv = sHome[im];
    float qx = qv.x, qy = qv.y, qz = qv.z, qq = qv.w;

    unsigned keys[KW];
    #pragma unroll
    for (int s = 0; s < KW; ++s) keys[s] = 0x7F800000u | (unsigned)s;  // sorted inf seeds

    float minv = 1e30f;

    for (int t = 0; t < NP / 8; ++t) {
        int jj = (t << 3) | wave;
        float4 h = sHome[jj];                                  // broadcast b128
        float dotj = dot_rn(qx, qy, qz, h.x, h.y, h.z);
        float d2 = __fsub_rn(__fadd_rn(qq, h.w), __fmul_rn(2.f, dotj));
        chain10(keys, (__float_as_uint(d2) & 0xFFFFF800u) | (unsigned)jj);
        float4 o = sOther[jj];                                 // broadcast b128
        float ex = qx - o.x, ey = qy - o.y, ez = qz - o.z;
        minv = fminf(minv, fmaf(ex, ex, fmaf(ey, ey, ez * ez)));
    }
    __syncthreads();   // all sOther reads done before kbuf aliasing writes

    // publish per-wave sorted top-10 + chamfer partial min
    #pragma unroll
    for (int s = 0; s < KW; ++s) kbuf[KIDX(s, wave, lane)] = keys[s];
    mbuf[wave * 64 + lane] = minv;
    __syncthreads();

    if (wave != 0) return;

    // ---------------- tail: wave 0, fully packed (64 lanes = 64 queries) ----------------
    // --- merge 8x10 -> sorted top-16 (insert sequence identical to R9/R10) ---
    unsigned k16[KN];
    #pragma unroll
    for (int s = 0; s < KW; ++s) k16[s] = keys[s];             // own sorted 10
    #pragma unroll
    for (int s = KW; s < KN; ++s) k16[s] = 0x7F800000u | (unsigned)s;  // seeds (> any real)
    for (int w = 1; w < 8; ++w) {
        #pragma unroll
        for (int s = 0; s < KW; ++s) chain16(k16, kbuf[KIDX(s, w, lane)]);
    }
    minv = fminf(fminf(fminf(mbuf[lane], mbuf[64 + lane]),
                       fminf(mbuf[128 + lane], mbuf[192 + lane])),
                 fminf(fminf(mbuf[256 + lane], mbuf[320 + lane]),
                       fminf(mbuf[384 + lane], mbuf[448 + lane])));

    // --- violation detect: slice may hide a top-16 member iff its 10th-best
    //     (kbuf slot 9, sorted) < pool 16th (k16[15]). Exact repair below. ---
    unsigned flags = 0;
    #pragma unroll
    for (int w = 0; w < 8; ++w)
        flags |= (kbuf[KIDX(KW - 1, w, lane)] < k16[15]) ? (1u << w) : 0u;

    if (__any(flags != 0)) {                 // ~0.07 expected events per LAUNCH
        #pragma unroll
        for (int s = 0; s < KN; ++s)
            k16[s] = flags ? (0x7F800000u | (unsigned)s) : k16[s];   // reinit flagged lanes
        for (int w = 0; w < 8; ++w) {
            #pragma unroll
            for (int s = 0; s < KW; ++s) {
                unsigned kk = kbuf[KIDX(s, w, lane)];
                bool use = (flags != 0) && !((flags >> w) & 1);
                chain16(k16, use ? kk : 0xFFFFFFFFu);          // inf = no-op
            }
        }
        for (int w = 0; w < 8; ++w) {
            if (__any((flags >> w) & 1)) {
                bool actw = ((flags >> w) & 1) != 0;
                for (int t = 0; t < NP / 8; ++t) {
                    int jj = (t << 3) | w;
                    float4 h = sHome[jj];
                    float dotj = dot_rn(qx, qy, qz, h.x, h.y, h.z);
                    float d2 = __fsub_rn(__fadd_rn(qq, h.w), __fmul_rn(2.f, dotj));
                    unsigned key = (__float_as_uint(d2) & 0xFFFFF800u) | (unsigned)jj;
                    chain16(k16, actw ? key : 0xFFFFFFFFu);
                }
            }
        }
    }

    // --- repulsion: k16 sorted ascending, slot 0 = self (d2=0) -> slots 1..4 ---
    float rep = 0.0f;
    if (predHome) {
        #pragma unroll
        for (int r = 1; r <= 4; ++r) {
            float d2 = __uint_as_float(k16[r] & 0xFFFFF800u);
            float dd = sqrtf(fmaxf(d2, 1e-12f));
            rep += fmaxf(0.02f - dd, 0.0f);
        }
    }

    // --- covariance over the 16-NN: gather from sHome (bit-identical values) ---
    float sx = 0.f, sy = 0.f, sz = 0.f;
    #pragma unroll
    for (int s = 0; s < KN; ++s) {
        float4 p = sHome[k16[s] & 0x7FFu];
        sx += p.x; sy += p.y; sz += p.z;
    }
    float mx = sx * (1.0f / KN), my = sy * (1.0f / KN), mz = sz * (1.0f / KN);
    float cxx = 0.f, cxy = 0.f, cxz = 0.f, cyy = 0.f, cyz = 0.f, czz = 0.f;
    #pragma unroll
    for (int s = 0; s < KN; ++s) {
        float4 p = sHome[k16[s] & 0x7FFu];
        float ax = p.x - mx;
        float ay = p.y - my;
        float az = p.z - mz;
        cxx += ax * ax; cxy += ax * ay; cxz += ax * az;
        cyy += ay * ay; cyz += ay * az; czz += az * az;
    }
    cxx *= (1.f / KN); cxy *= (1.f / KN); cxz *= (1.f / KN);
    cyy *= (1.f / KN); cyz *= (1.f / KN); czz *= (1.f / KN);

    // --- normal via faithful ssyevd emulation (register-resident) ---
    float nx, ny, nz;
    ssyevd3_evec0(cxx, cxy, cxz, cyy, cyz, czz, &nx, &ny, &nz);

    float* nout = predHome ? nP : nG;
    int gi = b * NP + im;
    nout[gi * 3 + 0] = nx;
    nout[gi * 3 + 1] = ny;
    nout[gi * 3 + 2] = nz;

    double part = (double)minv * (1.0 / (NB * NP))
                + (double)rep  * (0.1 / (NB * NP * 4));

    #pragma unroll
    for (int off = 32; off > 0; off >>= 1) part += __shfl_down(part, off);
    if (lane == 0) cdpart[bi] = part;
}

// ---------------------------------------------------------------------------
// Finalize: 1 block x 1024 threads (16 waves, 1 CU — L2-hot 384KB read hidden
// by 16-wave TLP). Phase A: normal-dot with the EXACT per-thread fp32 order of
// the old passing dot_kernel (vt = tid, stride 1024). Phase B: reduce 512
// cdpart doubles + dot partials, write out.
__global__ __launch_bounds__(1024) void fin_kernel(
    const float* __restrict__ nP, const float* __restrict__ nG,
    const double* __restrict__ cdpart, float* __restrict__ out)
{
    __shared__ double wc[16], wd[16];
    int tid = threadIdx.x;
    int wave = tid >> 6, lane = tid & 63;

    float s = 0.f;
    for (int i = tid; i < NB * NP; i += 1024)
        s += nP[3 * i] * nG[3 * i] + nP[3 * i + 1] * nG[3 * i + 1] + nP[3 * i + 2] * nG[3 * i + 2];
    double d = (double)s;

    double c = (tid < 512) ? cdpart[tid] : 0.0;

    #pragma unroll
    for (int off = 32; off > 0; off >>= 1) {
        c += __shfl_down(c, off);
        d += __shfl_down(d, off);
    }
    if (lane == 0) { wc[wave] = c; wd[wave] = d; }
    __syncthreads();
    if (tid == 0) {
        double a = 0.0, t = 0.0;
        #pragma unroll
        for (int w = 0; w < 16; ++w) { a += wc[w]; t += wd[w]; }
        out[0] = (float)(a - t * (0.01 / (NB * NP)) + 0.01);
    }
}

// ---------------------------------------------------------------------------
extern "C" void kernel_launch(void* const* d_in, const int* in_sizes, int n_in,
                              void* d_out, int out_size, void* d_ws, size_t ws_size,
                              hipStream_t stream)
{
    const float* pred = (const float*)d_in[0];
    const float* gt   = (const float*)d_in[1];

    // ws layout: nP (192KB) | nG (192KB) | cdpart (512 f64 = 4KB).
    // No memset needed: every slot is written before being read (stream order).
    char* base = (char*)d_ws;
    float*  nP     = (float*)base;
    float*  nG     = nP + (size_t)NB * NP * 3;
    double* cdpart = (double*)(nG + (size_t)NB * NP * 3);

    scan_kernel<<<dim3(NB * 32 * 2), dim3(512), 0, stream>>>(pred, gt, nP, nG, cdpart);
    fin_kernel<<<dim3(1), dim3(1024), 0, stream>>>(nP, nG, cdpart, (float*)d_out);
}